// Round 2
// baseline (75.551 us; speedup 1.0000x reference)
//
#include <hip/hip_runtime.h>
#include <math.h>

#define NQ 4
#define NL 2
#define ELEMS 2   // batch elements per thread. grid = B/(256*2) = 2048 blocks
                  // = 8 blocks/CU = 8 waves/SIMD — full wave-slot occupancy.
                  // (ELEMS=4 was grid-limited to 4 waves/SIMD.)

static __device__ __forceinline__ float uniform_sgpr(float x) {
    // Weights are grid-uniform: pin to SGPR so butterfly FMAs read them as
    // the single legal SGPR operand, freeing 16 VGPRs for 8-wave occupancy.
    return __int_as_float(__builtin_amdgcn_readfirstlane(__float_as_int(x)));
}

// One thread = ELEMS batch elements; 16-real statevector in registers.
// Index convention: k = b0*8 + b1*4 + b2*2 + b3 (wire 0 = MSB), matching the
// reference's [2,2,2,2] flatten and its z-sign table.
__global__ __launch_bounds__(256, 8) void qsim_kernel(
        const float4* __restrict__ x,      // [B] of float4 (x[:,0..3])
        const float*  __restrict__ w,      // [NL*NQ] weights
        float4* __restrict__ out,          // [B] of float4 (out[:,0..3])
        int B) {
    const int tid   = blockIdx.x * blockDim.x + threadIdx.x;
    const int total = gridDim.x * blockDim.x;   // grid stride

    // Weight half-angle trig — once per thread, then pinned uniform (SGPR).
    float wc[NL * NQ], wsn[NL * NQ];
#pragma unroll
    for (int i = 0; i < NL * NQ; ++i) {
        float s, c;
        __sincosf(0.5f * w[i], &s, &c);
        wc[i]  = uniform_sgpr(c);
        wsn[i] = uniform_sgpr(s);
    }

    // Hoist both loads: 2 dwordx4 in flight before any compute.
    float4 xv[ELEMS];
#pragma unroll
    for (int e = 0; e < ELEMS; ++e) {
        const int b = tid + e * total;           // coalesced per iteration
        xv[e] = (b < B) ? x[b] : make_float4(0.f, 0.f, 0.f, 0.f);
    }

#pragma unroll
    for (int e = 0; e < ELEMS; ++e) {
        const int b = tid + e * total;
        if (b >= B) continue;

        const float4 xa = xv[e];

        // Data encoding RY(x_i) on |0..0>: product state.
        float c0, s0, c1, s1, c2, s2, c3, s3;
        __sincosf(0.5f * xa.x, &s0, &c0);
        __sincosf(0.5f * xa.y, &s1, &c1);
        __sincosf(0.5f * xa.z, &s2, &c2);
        __sincosf(0.5f * xa.w, &s3, &c3);

        const float a00 = c0 * c1, a01 = c0 * s1, a10 = s0 * c1, a11 = s0 * s1;
        const float g00 = c2 * c3, g01 = c2 * s3, g10 = s2 * c3, g11 = s2 * s3;

        float st[16];
        st[ 0] = a00 * g00; st[ 1] = a00 * g01; st[ 2] = a00 * g10; st[ 3] = a00 * g11;
        st[ 4] = a01 * g00; st[ 5] = a01 * g01; st[ 6] = a01 * g10; st[ 7] = a01 * g11;
        st[ 8] = a10 * g00; st[ 9] = a10 * g01; st[10] = a10 * g10; st[11] = a10 * g11;
        st[12] = a11 * g00; st[13] = a11 * g01; st[14] = a11 * g10; st[15] = a11 * g11;

        // Variational layers: RY(weights[l][q]) per wire, then CNOT chain.
#pragma unroll
        for (int l = 0; l < NL; ++l) {
#pragma unroll
            for (int q = 0; q < NQ; ++q) {
                const float c = wc[l * NQ + q];
                const float s = wsn[l * NQ + q];
                const int str = 8 >> q;
#pragma unroll
                for (int k = 0; k < 16; ++k) {
                    if ((k & str) == 0) {
                        const float u = st[k], v = st[k + str];
                        st[k]       = c * u - s * v;
                        st[k + str] = s * u + c * v;
                    }
                }
            }
            // CNOT(ctrl=q, tgt=q+1): compile-time register permutation — free.
#pragma unroll
            for (int q = 0; q < NQ - 1; ++q) {
                const int cs = 8 >> q;
                const int ts = 8 >> (q + 1);
#pragma unroll
                for (int k = 0; k < 16; ++k) {
                    if ((k & cs) != 0 && (k & ts) == 0) {
                        const float t = st[k];
                        st[k] = st[k + ts];
                        st[k + ts] = t;
                    }
                }
            }
        }

        // probs + signed sums.
        float p[16];
#pragma unroll
        for (int k = 0; k < 16; ++k) p[k] = st[k] * st[k];

        float q2[8];
        float o3 = 0.f;
#pragma unroll
        for (int i = 0; i < 8; ++i) {
            q2[i] = p[2 * i] + p[2 * i + 1];
            o3   += p[2 * i] - p[2 * i + 1];
        }
        float r4[4];
        float o2 = 0.f;
#pragma unroll
        for (int i = 0; i < 4; ++i) {
            r4[i] = q2[2 * i] + q2[2 * i + 1];
            o2   += q2[2 * i] - q2[2 * i + 1];
        }
        const float o1 = (r4[0] - r4[1]) + (r4[2] - r4[3]);
        const float o0 = (r4[0] + r4[1]) - (r4[2] + r4[3]);

        out[b] = make_float4(o0, o1, o2, o3);
    }
}

extern "C" void kernel_launch(void* const* d_in, const int* in_sizes, int n_in,
                              void* d_out, int out_size, void* d_ws, size_t ws_size,
                              hipStream_t stream) {
    const float* x = (const float*)d_in[0];        // [B,4]
    const float* w = (const float*)d_in[1];        // [2,4]
    float* out = (float*)d_out;                    // [B,4]

    int B = in_sizes[0] / 4;

    int block = 256;
    int per_block = block * ELEMS;
    int grid = (B + per_block - 1) / per_block;    // 2048 for B=1M
    qsim_kernel<<<grid, block, 0, stream>>>(
        (const float4*)x, w, (float4*)out, B);
}